// Round 2
// baseline (23271.797 us; speedup 1.0000x reference)
//
#include <hip/hip_runtime.h>
#include <cmath>

#define NIN   128
#define NHID  32
#define CTS   16384
#define NCT   16
#define NBAGS (CTS / NCT)
#define CAP   256            // max rows per segment bucket (Poisson(122) -> max ~170)
#define SEG_STRIDE 33        // fallback path: 32 sums + denom

// ---------------------------------------------------------------------------
// Fast path: bucket rows by segment (1 int atomic/row), then gather+reduce.
// ---------------------------------------------------------------------------

__global__ __launch_bounds__(256) void scatter_kernel(
    const int* __restrict__ batch, int* __restrict__ cnt,
    int* __restrict__ slots, int n)
{
    int i = blockIdx.x * 256 + threadIdx.x;
    if (i >= n) return;
    int s = batch[i];
    int pos = atomicAdd(&cnt[s * 16], 1);   // cnt padded: one 64B line per segment
    if (pos < CAP) slots[(size_t)s * CAP + pos] = i;
}

// One wave per segment; 2 waves (2 segments) per block share W1 in LDS.
__global__ __launch_bounds__(128) void seg_kernel(
    const float* __restrict__ X,
    const float* __restrict__ W1,
    const float* __restrict__ b1,
    const float* __restrict__ wc,
    const float* __restrict__ bc,
    const int*   __restrict__ cnt,
    const int*   __restrict__ slots,
    float* __restrict__ P)
{
    __shared__ __align__(16) float w1s[NIN * NHID];   // 16 KB, [k][j]
    __shared__ float b1s[NHID];
    __shared__ float wcs[NHID];
    __shared__ float red[2][16][NHID + 1];            // per-wave reduce buffer

    const int tid = threadIdx.x;
    for (int i = tid; i < NIN * NHID / 4; i += 128)
        ((float4*)w1s)[i] = ((const float4*)W1)[i];
    if (tid < NHID) { b1s[tid] = b1[tid]; wcs[tid] = wc[tid]; }
    __syncthreads();

    const int w    = tid >> 6;
    const int lane = tid & 63;
    const int s    = blockIdx.x * 2 + w;
    const int m    = min(cnt[s * 16], CAP);
    const float bc0 = bc[0];

    float acc[NHID];
    float esum = 0.f;
#pragma unroll
    for (int j = 0; j < NHID; ++j) acc[j] = 0.f;

    for (int p = lane; p < m; p += 64) {
        const int r = slots[(size_t)s * CAP + p];
        const float4* __restrict__ xp = (const float4*)(X + (size_t)r * NIN);

        float racc[NHID];
#pragma unroll
        for (int j = 0; j < NHID; ++j) racc[j] = 0.f;

#pragma unroll
        for (int kc = 0; kc < NIN / 32; ++kc) {
            float4 xv[8];
#pragma unroll
            for (int q = 0; q < 8; ++q) xv[q] = xp[kc * 8 + q];
#pragma unroll
            for (int q = 0; q < 8; ++q) {
                const float a[4] = {xv[q].x, xv[q].y, xv[q].z, xv[q].w};
#pragma unroll
                for (int kk = 0; kk < 4; ++kk) {
                    const int k = kc * 32 + q * 4 + kk;
                    const float4* __restrict__ wrow = (const float4*)(w1s + k * NHID);
                    const float u = a[kk];
#pragma unroll
                    for (int jq = 0; jq < 8; ++jq) {
                        const float4 wv = wrow[jq];    // wave-uniform -> LDS broadcast
                        racc[jq*4+0] += u * wv.x;
                        racc[jq*4+1] += u * wv.y;
                        racc[jq*4+2] += u * wv.z;
                        racc[jq*4+3] += u * wv.w;
                    }
                }
            }
        }

        float sc = bc0;
#pragma unroll
        for (int j = 0; j < NHID; ++j) {
            float h = fmaxf(racc[j] + b1s[j], 0.f);
            racc[j] = h;
            sc += h * wcs[j];
        }
        const float e = expf(sc);
        esum += e;
#pragma unroll
        for (int j = 0; j < NHID; ++j) acc[j] += e * racc[j];
    }

    // fold 64 lanes -> 16 lanes in-register
#pragma unroll
    for (int j = 0; j < NHID; ++j) {
        acc[j] += __shfl_xor(acc[j], 32);
        acc[j] += __shfl_xor(acc[j], 16);
    }
    esum += __shfl_xor(esum, 32);
    esum += __shfl_xor(esum, 16);

    if (lane < 16) {
#pragma unroll
        for (int j = 0; j < NHID; ++j) red[w][lane][j] = acc[j];
        red[w][lane][NHID] = esum;
    }
    __syncthreads();

    float t = 0.f;
    if (lane < NHID + 1) {
#pragma unroll
        for (int r = 0; r < 16; ++r) t += red[w][r][lane];
    }
    const float den = __shfl(t, NHID);   // lane 32 holds the denom sum
    if (lane < NHID) {
        const float pj = den > 0.f ? t / den : 0.f;   // empty segment -> zero row
        P[(size_t)s * NHID + lane] = pj;              // coalesced 128B write
    }
}

// Stage 3: per-bag cell-type softmax + output projection (P already normalized).
__global__ __launch_bounds__(256) void bags_kernel(
    const float* __restrict__ P,
    const float* __restrict__ wct,
    const float* __restrict__ bct,
    const float* __restrict__ Wout,
    const float* __restrict__ bout,
    float* __restrict__ out)
{
    const int b = blockIdx.x * blockDim.x + threadIdx.x;
    if (b >= NBAGS) return;

    float wctr[NHID], wor[NHID];
#pragma unroll
    for (int j = 0; j < NHID; ++j) { wctr[j] = wct[j]; wor[j] = Wout[j]; }
    const float bct0 = bct[0];

    float logit[NCT], dout[NCT];
#pragma unroll
    for (int ct = 0; ct < NCT; ++ct) {
        const float* p = P + (size_t)(b * NCT + ct) * NHID;
        float t = 0.f, d = 0.f;
#pragma unroll
        for (int j = 0; j < NHID; ++j) {
            const float pj = p[j];
            t += pj * wctr[j];
            d += pj * wor[j];
        }
        logit[ct] = t + bct0;
        dout[ct]  = d;
    }

    float mx = logit[0];
#pragma unroll
    for (int ct = 1; ct < NCT; ++ct) mx = fmaxf(mx, logit[ct]);
    float den = 0.f, accv = 0.f;
#pragma unroll
    for (int ct = 0; ct < NCT; ++ct) {
        const float e = expf(logit[ct] - mx);
        den += e;
        accv += e * dout[ct];
    }
    out[b] = accv / den + bout[0];
}

// ---------------------------------------------------------------------------
// Fallback path (ws too small): round-0 atomic accumulation.
// ---------------------------------------------------------------------------

__global__ __launch_bounds__(256) void rows_kernel_atomic(
    const float* __restrict__ X, const float* __restrict__ W1,
    const float* __restrict__ b1, const float* __restrict__ wc,
    const float* __restrict__ bc, const int* __restrict__ batch,
    float* __restrict__ segacc, int n)
{
    __shared__ __align__(16) float w1s[NIN * NHID];
    __shared__ float b1s[NHID];
    __shared__ float wcs[NHID];
    const int tid = threadIdx.x;
    for (int i = tid; i < NIN * NHID; i += 256) w1s[i] = W1[i];
    if (tid < NHID) { b1s[tid] = b1[tid]; wcs[tid] = wc[tid]; }
    __syncthreads();
    const long long r0 = (long long)blockIdx.x * 256 + tid;
    if (r0 >= n) return;
    const float4* xp = (const float4*)(X + (size_t)r0 * NIN);
    float acc[NHID];
#pragma unroll
    for (int j = 0; j < NHID; ++j) acc[j] = 0.f;
#pragma unroll
    for (int kc = 0; kc < NIN / 32; ++kc) {
        float4 xv[8];
#pragma unroll
        for (int q = 0; q < 8; ++q) xv[q] = xp[kc * 8 + q];
#pragma unroll
        for (int q = 0; q < 8; ++q) {
            const float a[4] = {xv[q].x, xv[q].y, xv[q].z, xv[q].w};
#pragma unroll
            for (int kk = 0; kk < 4; ++kk) {
                const float4* wrow = (const float4*)(w1s + (kc*32 + q*4 + kk) * NHID);
                const float u = a[kk];
#pragma unroll
                for (int jq = 0; jq < 8; ++jq) {
                    const float4 wv = wrow[jq];
                    acc[jq*4+0] += u * wv.x; acc[jq*4+1] += u * wv.y;
                    acc[jq*4+2] += u * wv.z; acc[jq*4+3] += u * wv.w;
                }
            }
        }
    }
    float sc = bc[0];
#pragma unroll
    for (int j = 0; j < NHID; ++j) {
        float h = fmaxf(acc[j] + b1s[j], 0.f); acc[j] = h; sc += h * wcs[j];
    }
    const float e = expf(sc);
    float* p = segacc + (size_t)batch[r0] * SEG_STRIDE;
#pragma unroll
    for (int j = 0; j < NHID; ++j) atomicAdd(p + j, e * acc[j]);
    atomicAdd(p + NHID, e);
}

__global__ __launch_bounds__(256) void bags_kernel_fb(
    const float* __restrict__ segacc, const float* __restrict__ wct,
    const float* __restrict__ bct, const float* __restrict__ Wout,
    const float* __restrict__ bout, float* __restrict__ out)
{
    const int b = blockIdx.x * blockDim.x + threadIdx.x;
    if (b >= NBAGS) return;
    float wctr[NHID], wor[NHID];
#pragma unroll
    for (int j = 0; j < NHID; ++j) { wctr[j] = wct[j]; wor[j] = Wout[j]; }
    float logit[NCT], dout[NCT];
#pragma unroll
    for (int ct = 0; ct < NCT; ++ct) {
        const float* p = segacc + (size_t)(b * NCT + ct) * SEG_STRIDE;
        const float den = p[NHID];
        const float inv = den > 0.f ? 1.f / den : 0.f;
        float t = 0.f, d = 0.f;
#pragma unroll
        for (int j = 0; j < NHID; ++j) { const float pj = p[j]*inv; t += pj*wctr[j]; d += pj*wor[j]; }
        logit[ct] = t + bct[0];
        dout[ct]  = d;
    }
    float mx = logit[0];
#pragma unroll
    for (int ct = 1; ct < NCT; ++ct) mx = fmaxf(mx, logit[ct]);
    float den = 0.f, accv = 0.f;
#pragma unroll
    for (int ct = 0; ct < NCT; ++ct) {
        const float e = expf(logit[ct] - mx);
        den += e; accv += e * dout[ct];
    }
    out[b] = accv / den + bout[0];
}

// ---------------------------------------------------------------------------

extern "C" void kernel_launch(void* const* d_in, const int* in_sizes, int n_in,
                              void* d_out, int out_size, void* d_ws, size_t ws_size,
                              hipStream_t stream)
{
    const float* X    = (const float*)d_in[0];
    const float* W1   = (const float*)d_in[1];
    const float* b1   = (const float*)d_in[2];
    const float* wc   = (const float*)d_in[3];
    const float* bc   = (const float*)d_in[4];
    const float* wct  = (const float*)d_in[5];
    const float* bct  = (const float*)d_in[6];
    const float* Wout = (const float*)d_in[7];
    const float* bout = (const float*)d_in[8];
    const int*   batch= (const int*)d_in[9];
    const int n = in_sizes[9];

    const size_t cnt_bytes  = (size_t)CTS * 16 * sizeof(int);     // 1 MB (line-padded)
    const size_t slot_bytes = (size_t)CTS * CAP * sizeof(int);    // 16 MB
    const size_t p_bytes    = (size_t)CTS * NHID * sizeof(float); // 2 MB
    const size_t need = cnt_bytes + slot_bytes + p_bytes;

    if (ws_size >= need) {
        int*   cnt   = (int*)d_ws;
        int*   slots = cnt + (size_t)CTS * 16;
        float* P     = (float*)(slots + (size_t)CTS * CAP);

        hipMemsetAsync(cnt, 0, cnt_bytes, stream);
        scatter_kernel<<<(n + 255) / 256, 256, 0, stream>>>(batch, cnt, slots, n);
        seg_kernel<<<CTS / 2, 128, 0, stream>>>(X, W1, b1, wc, bc, cnt, slots, P);
        bags_kernel<<<(NBAGS + 255) / 256, 256, 0, stream>>>(
            P, wct, bct, Wout, bout, (float*)d_out);
    } else {
        float* segacc = (float*)d_ws;
        hipMemsetAsync(segacc, 0, (size_t)CTS * SEG_STRIDE * sizeof(float), stream);
        rows_kernel_atomic<<<(n + 255) / 256, 256, 0, stream>>>(
            X, W1, b1, wc, bc, batch, segacc, n);
        bags_kernel_fb<<<(NBAGS + 255) / 256, 256, 0, stream>>>(
            segacc, wct, bct, Wout, bout, (float*)d_out);
    }
}

// Round 3
// 492.366 us; speedup vs baseline: 47.2652x; 47.2652x over previous
//
#include <hip/hip_runtime.h>
#include <cmath>

#define NIN   128
#define NHID  32
#define CTS   16384
#define NCT   16
#define NBAGS (CTS / NCT)
#define CAP   256            // max rows per segment bucket (Poisson(122) -> max ~170)
#define SEG_STRIDE 33        // fallback path only

// ---------------------------------------------------------------------------
// Fast path: bucket rows by segment (1 int atomic/row), then gather+reduce.
// ---------------------------------------------------------------------------

__global__ __launch_bounds__(256) void scatter_kernel(
    const int* __restrict__ batch, int* __restrict__ cnt,
    int* __restrict__ slots, int n)
{
    int i = blockIdx.x * 256 + threadIdx.x;
    if (i >= n) return;
    int s = batch[i];
    int pos = atomicAdd(&cnt[s * 16], 1);   // cnt padded: one 64B line per segment
    if (pos < CAP) slots[(size_t)s * CAP + pos] = i;
}

// One wave per segment, 4 waves (4 segments) per block.
// W1/b1/wc are read with wave-uniform indices -> scalar loads (SGPR operands),
// so per-thread VGPR state is just acc[32]+racc[32]+x stream (~100 VGPR, no spill).
__global__ __launch_bounds__(256) void seg_kernel(
    const float* __restrict__ X,
    const float* __restrict__ W1,     // [128][32] row-major
    const float* __restrict__ b1,
    const float* __restrict__ wc,
    const float* __restrict__ bc,
    const int*   __restrict__ cnt,
    const int*   __restrict__ slots,
    float* __restrict__ P)
{
    __shared__ float red[4][16][NHID + 2];

    const int tid  = threadIdx.x;
    const int w    = tid >> 6;
    const int lane = tid & 63;
    const int s    = blockIdx.x * 4 + w;
    const int m    = min(cnt[s * 16], CAP);
    const float bc0 = bc[0];

    float acc[NHID];
    float esum = 0.f;
#pragma unroll
    for (int j = 0; j < NHID; ++j) acc[j] = 0.f;

    for (int p = lane; p < m; p += 64) {
        const int r = slots[(size_t)s * CAP + p];
        const float4* __restrict__ xp = (const float4*)(X + (size_t)r * NIN);

        float racc[NHID];
#pragma unroll
        for (int j = 0; j < NHID; ++j) racc[j] = 0.f;

#pragma unroll 4
        for (int kc = 0; kc < NIN / 4; ++kc) {
            const float4 xv = xp[kc];
            const float xa[4] = {xv.x, xv.y, xv.z, xv.w};
#pragma unroll
            for (int kk = 0; kk < 4; ++kk) {
                const int k = kc * 4 + kk;
                const float u = xa[kk];
                const float* __restrict__ wrow = W1 + k * NHID;   // uniform -> s_load
#pragma unroll
                for (int j = 0; j < NHID; ++j)
                    racc[j] = fmaf(u, wrow[j], racc[j]);
            }
        }

        float sc = bc0;
#pragma unroll
        for (int j = 0; j < NHID; ++j) {
            const float h = fmaxf(racc[j] + b1[j], 0.f);   // b1/wc uniform -> s_load
            racc[j] = h;
            sc += h * wc[j];
        }
        const float e = expf(sc);
        esum += e;
#pragma unroll
        for (int j = 0; j < NHID; ++j) acc[j] = fmaf(e, racc[j], acc[j]);
    }

    // fold 64 lanes -> 16 lanes in-register
#pragma unroll
    for (int j = 0; j < NHID; ++j) {
        acc[j] += __shfl_xor(acc[j], 32);
        acc[j] += __shfl_xor(acc[j], 16);
    }
    esum += __shfl_xor(esum, 32);
    esum += __shfl_xor(esum, 16);

    if (lane < 16) {
#pragma unroll
        for (int j = 0; j < NHID; ++j) red[w][lane][j] = acc[j];
        red[w][lane][NHID] = esum;
    }
    __syncthreads();

    float t = 0.f;
    if (lane < NHID + 1) {
#pragma unroll
        for (int r = 0; r < 16; ++r) t += red[w][r][lane];
    }
    const float den = __shfl(t, NHID);   // lane 32 holds the denom sum
    if (lane < NHID) {
        const float pj = den > 0.f ? t / den : 0.f;   // empty segment -> zero row
        P[(size_t)s * NHID + lane] = pj;              // coalesced 128B write
    }
}

// Stage 3: per-bag cell-type softmax + output projection (P already normalized).
__global__ __launch_bounds__(256) void bags_kernel(
    const float* __restrict__ P,
    const float* __restrict__ wct,
    const float* __restrict__ bct,
    const float* __restrict__ Wout,
    const float* __restrict__ bout,
    float* __restrict__ out)
{
    const int b = blockIdx.x * blockDim.x + threadIdx.x;
    if (b >= NBAGS) return;

    float logit[NCT], dout[NCT];
#pragma unroll
    for (int ct = 0; ct < NCT; ++ct) {
        const float* p = P + (size_t)(b * NCT + ct) * NHID;
        float t = 0.f, d = 0.f;
#pragma unroll
        for (int j = 0; j < NHID; ++j) {
            const float pj = p[j];
            t += pj * wct[j];      // uniform -> s_load
            d += pj * Wout[j];
        }
        logit[ct] = t + bct[0];
        dout[ct]  = d;
    }

    float mx = logit[0];
#pragma unroll
    for (int ct = 1; ct < NCT; ++ct) mx = fmaxf(mx, logit[ct]);
    float den = 0.f, accv = 0.f;
#pragma unroll
    for (int ct = 0; ct < NCT; ++ct) {
        const float e = expf(logit[ct] - mx);
        den += e;
        accv += e * dout[ct];
    }
    out[b] = accv / den + bout[0];
}

// ---------------------------------------------------------------------------
// Fallback path (ws too small): atomic accumulation, same scalar-W1 trick.
// ---------------------------------------------------------------------------

__global__ __launch_bounds__(256) void rows_kernel_atomic(
    const float* __restrict__ X, const float* __restrict__ W1,
    const float* __restrict__ b1, const float* __restrict__ wc,
    const float* __restrict__ bc, const int* __restrict__ batch,
    float* __restrict__ segacc, int n)
{
    const long long r0 = (long long)blockIdx.x * 256 + threadIdx.x;
    if (r0 >= n) return;
    const float4* xp = (const float4*)(X + (size_t)r0 * NIN);
    float acc[NHID];
#pragma unroll
    for (int j = 0; j < NHID; ++j) acc[j] = 0.f;
#pragma unroll 4
    for (int kc = 0; kc < NIN / 4; ++kc) {
        const float4 xv = xp[kc];
        const float xa[4] = {xv.x, xv.y, xv.z, xv.w};
#pragma unroll
        for (int kk = 0; kk < 4; ++kk) {
            const float* wrow = W1 + (kc * 4 + kk) * NHID;
            const float u = xa[kk];
#pragma unroll
            for (int j = 0; j < NHID; ++j) acc[j] = fmaf(u, wrow[j], acc[j]);
        }
    }
    float sc = bc[0];
#pragma unroll
    for (int j = 0; j < NHID; ++j) {
        const float h = fmaxf(acc[j] + b1[j], 0.f); acc[j] = h; sc += h * wc[j];
    }
    const float e = expf(sc);
    float* p = segacc + (size_t)batch[r0] * SEG_STRIDE;
#pragma unroll
    for (int j = 0; j < NHID; ++j) atomicAdd(p + j, e * acc[j]);
    atomicAdd(p + NHID, e);
}

__global__ __launch_bounds__(256) void bags_kernel_fb(
    const float* __restrict__ segacc, const float* __restrict__ wct,
    const float* __restrict__ bct, const float* __restrict__ Wout,
    const float* __restrict__ bout, float* __restrict__ out)
{
    const int b = blockIdx.x * blockDim.x + threadIdx.x;
    if (b >= NBAGS) return;
    float logit[NCT], dout[NCT];
#pragma unroll
    for (int ct = 0; ct < NCT; ++ct) {
        const float* p = segacc + (size_t)(b * NCT + ct) * SEG_STRIDE;
        const float den = p[NHID];
        const float inv = den > 0.f ? 1.f / den : 0.f;
        float t = 0.f, d = 0.f;
#pragma unroll
        for (int j = 0; j < NHID; ++j) { const float pj = p[j]*inv; t += pj*wct[j]; d += pj*Wout[j]; }
        logit[ct] = t + bct[0];
        dout[ct]  = d;
    }
    float mx = logit[0];
#pragma unroll
    for (int ct = 1; ct < NCT; ++ct) mx = fmaxf(mx, logit[ct]);
    float den = 0.f, accv = 0.f;
#pragma unroll
    for (int ct = 0; ct < NCT; ++ct) {
        const float e = expf(logit[ct] - mx);
        den += e; accv += e * dout[ct];
    }
    out[b] = accv / den + bout[0];
}

// ---------------------------------------------------------------------------

extern "C" void kernel_launch(void* const* d_in, const int* in_sizes, int n_in,
                              void* d_out, int out_size, void* d_ws, size_t ws_size,
                              hipStream_t stream)
{
    const float* X    = (const float*)d_in[0];
    const float* W1   = (const float*)d_in[1];
    const float* b1   = (const float*)d_in[2];
    const float* wc   = (const float*)d_in[3];
    const float* bc   = (const float*)d_in[4];
    const float* wct  = (const float*)d_in[5];
    const float* bct  = (const float*)d_in[6];
    const float* Wout = (const float*)d_in[7];
    const float* bout = (const float*)d_in[8];
    const int*   batch= (const int*)d_in[9];
    const int n = in_sizes[9];

    const size_t cnt_bytes  = (size_t)CTS * 16 * sizeof(int);     // 1 MB (line-padded)
    const size_t slot_bytes = (size_t)CTS * CAP * sizeof(int);    // 16 MB
    const size_t p_bytes    = (size_t)CTS * NHID * sizeof(float); // 2 MB
    const size_t need = cnt_bytes + slot_bytes + p_bytes;

    if (ws_size >= need) {
        int*   cnt   = (int*)d_ws;
        int*   slots = cnt + (size_t)CTS * 16;
        float* P     = (float*)(slots + (size_t)CTS * CAP);

        hipMemsetAsync(cnt, 0, cnt_bytes, stream);
        scatter_kernel<<<(n + 255) / 256, 256, 0, stream>>>(batch, cnt, slots, n);
        seg_kernel<<<CTS / 4, 256, 0, stream>>>(X, W1, b1, wc, bc, cnt, slots, P);
        bags_kernel<<<(NBAGS + 255) / 256, 256, 0, stream>>>(
            P, wct, bct, Wout, bout, (float*)d_out);
    } else {
        float* segacc = (float*)d_ws;
        hipMemsetAsync(segacc, 0, (size_t)CTS * SEG_STRIDE * sizeof(float), stream);
        rows_kernel_atomic<<<(n + 255) / 256, 256, 0, stream>>>(
            X, W1, b1, wc, bc, batch, segacc, n);
        bags_kernel_fb<<<(NBAGS + 255) / 256, 256, 0, stream>>>(
            segacc, wct, bct, Wout, bout, (float*)d_out);
    }
}